// Round 6
// baseline (462.275 us; speedup 1.0000x reference)
//
#include <hip/hip_runtime.h>

typedef _Float16 f16;
typedef __attribute__((ext_vector_type(8))) _Float16 half8;
typedef __attribute__((ext_vector_type(2))) _Float16 half2v;
typedef __attribute__((ext_vector_type(4))) float float4v;

#define MODE_QK 0
#define MODE_V 1
#define MODE_PV 2
#define MODE_PROJ 3

// B=8 N=512 P=16 C=512 H=8 HD=64 E=1024
// ws layout (bytes):
//   0         : xf16 [B,N,P,C] f16 (67108864)   -> reused as ypre [B,N,P,C]
//   67108864  : vT   [B,H,E',N] f16 (67108864)  (E' channel order = p*64+dd)
//   134217728 : xmean[B,N,C]   f16 (4194304)
//   138412032 : WT   [1536,512]f16 (1572864)    (Wqkv transposed)
//   139984896 : WpT  [512,512] f16 (524288)
//   140509184 : q    [B,H,N,64]f16 (4194304)
//   144703488 : k    [B,H,N,64]f16 (4194304)

__device__ __forceinline__ void gload16(const f16* g, f16* l) {
    __builtin_amdgcn_global_load_lds(
        (const __attribute__((address_space(1))) void*)g,
        (__attribute__((address_space(3))) void*)l, 16, 0, 0);
}

// merged: blocks [0,4096) do x prep; blocks [4096,8192) do weight transpose
__global__ __launch_bounds__(256) void prep_kernel(
    const float* __restrict__ x, const float* __restrict__ mask,
    const float* __restrict__ Wqkv, const float* __restrict__ Wproj,
    f16* __restrict__ xf, f16* __restrict__ xmean,
    f16* __restrict__ WT, f16* __restrict__ WpT)
{
    if (blockIdx.x >= 4096) {
        int idx = (blockIdx.x - 4096) * 256 + threadIdx.x;   // 1048576 total
        if (idx < 1536 * 512) {
            int d = idx >> 9, c = idx & 511;
            WT[idx] = (f16)Wqkv[c * 1536 + d];
        } else {
            int i2 = idx - 1536 * 512;
            int d = i2 >> 9, c = i2 & 511;
            WpT[i2] = (f16)Wproj[c * 512 + d];
        }
        return;
    }
    int bn = blockIdx.x;           // b*512+n
    int t = threadIdx.x;           // 256
    const float* xrow = x + (size_t)bn * 16 * 512;
    const float* mrow = mask + (size_t)bn * 16;
    float msum = 0.f;
    #pragma unroll
    for (int p = 0; p < 16; p++) msum += mrow[p];
    int c = t * 2;
    float a0 = 0.f, a1 = 0.f;
    #pragma unroll
    for (int p = 0; p < 16; p++) {
        float2 v = *(const float2*)(xrow + p * 512 + c);
        float m = mrow[p];
        a0 += m * v.x; a1 += m * v.y;
        half2v h; h[0] = (f16)v.x; h[1] = (f16)v.y;
        *(half2v*)(xf + (size_t)bn * 16 * 512 + p * 512 + c) = h;
    }
    float inv = 1.f / msum;
    half2v hm; hm[0] = (f16)(a0 * inv); hm[1] = (f16)(a1 * inv);
    *(half2v*)(xmean + (size_t)bn * 512 + c) = hm;
}

// 128x128 tile, K=512, BK=32, 256 threads = 4 waves in 2x2; each wave 64x64
// (4x4 fragments of 16x16x32).
// T4 counted-vmcnt 3-deep ring: prologue stages S0,S1; each iter
// {s_waitcnt vmcnt(4); s_barrier; stage S(t+2); ds_read+MFMA buf(t)}.
// T1: bijective chunked XCD swizzle. T2: source-pre-swizzled 16B-slot XOR.
// MFMA A/B frag: row = lane&15, k = (lane>>4)*8 + j.
// C/D: col = lane&15, row = (lane>>4)*4 + reg.
// Epilogue: per-WAVE private LDS bounce (no barriers), coalesced stores.
template<int MODE, int NXB, int NYB>
__global__ __launch_bounds__(256) void gemm128(
    const f16* __restrict__ pA, const f16* __restrict__ pA2,
    const f16* __restrict__ pB,
    f16* __restrict__ outa, f16* __restrict__ outb,
    float* __restrict__ outf, const float* __restrict__ bias)
{
    // 49152 B: ring of 3 x (As 8KB + Bs 8KB); epilogue reuses as bounce.
    __shared__ __align__(16) f16 sm[24576];
    const int t = threadIdx.x;
    const int lane = t & 63;
    const int w = t >> 6;
    const int wm = w & 1, wn = w >> 1;
    const int quad = lane >> 4, l15 = lane & 15;

    const int chunk = (int)gridDim.x >> 3;
    const int L = ((int)blockIdx.x & 7) * chunk + ((int)blockIdx.x >> 3);
    const int xb = L & ((1 << NXB) - 1);
    const int rest = L >> NXB;
    const int yb = rest & ((1 << NYB) - 1);
    const int z = rest >> NYB;
    const int n0 = xb * 128;
    const int m0 = yb * 128;
    int vb = 0, vp = 0;

    const f16* Abase; size_t sA;
    const f16* Bbase; size_t sB;
    if constexpr (MODE == MODE_QK) {
        if (n0 < 512) { Abase = pA;  sA = 8192; }   // x p=0 slice
        else          { Abase = pA2; sA = 512;  }   // xmean
        Bbase = pB; sB = 512;                       // WT rows
    } else if constexpr (MODE == MODE_V) {
        vb = z >> 4; vp = z & 15;
        Abase = pA; sA = 512;                       // WvT rows
        Bbase = pB + ((size_t)vb * 512 * 16 + vp) * 512; sB = 8192; // x[b,:,p,:]
    } else {
        Abase = pA; sA = 512;                       // ypre rows
        Bbase = pB; sB = 512;                       // WpT rows
    }

    const int rlo = (lane >> 2);
    const int kof = (((lane & 3) ^ ((rlo >> 1) & 3)) * 8);
    const f16* ga0 = Abase + (size_t)(m0 + w * 16 + rlo) * sA + kof;
    const f16* ga1 = Abase + (size_t)(m0 + (w + 4) * 16 + rlo) * sA + kof;
    const f16* gb0 = Bbase + (size_t)(n0 + w * 16 + rlo) * sB + kof;
    const f16* gb1 = Bbase + (size_t)(n0 + (w + 4) * 16 + rlo) * sB + kof;

    float4v acc[4][4];
    #pragma unroll
    for (int i = 0; i < 4; i++)
        #pragma unroll
        for (int j = 0; j < 4; j++)
            acc[i][j] = (float4v){0.f, 0.f, 0.f, 0.f};

    const int sws = (l15 >> 1) & 3;         // T2 read-side swizzle

#define STAGE(dst)                                                     \
    do {                                                               \
        f16* d_ = (dst);                                               \
        gload16(ga0, d_ + w * 512); gload16(ga1, d_ + (w + 4) * 512);  \
        gload16(gb0, d_ + 4096 + w * 512);                             \
        gload16(gb1, d_ + 4096 + (w + 4) * 512);                       \
        ga0 += 32; ga1 += 32; gb0 += 32; gb1 += 32;                    \
    } while (0)

#define COMPUTE(buf)                                                         \
    do {                                                                     \
        const f16* Asr_ = (buf);                                             \
        const f16* Bsr_ = Asr_ + 4096;                                       \
        half8 af[4], bf[4];                                                  \
        _Pragma("unroll")                                                    \
        for (int mi = 0; mi < 4; mi++)                                       \
            af[mi] = *(const half8*)&Asr_[(wm * 64 + mi * 16 + l15) * 32 +   \
                                          ((quad ^ sws) * 8)];               \
        _Pragma("unroll")                                                    \
        for (int ni = 0; ni < 4; ni++)                                       \
            bf[ni] = *(const half8*)&Bsr_[(wn * 64 + ni * 16 + l15) * 32 +   \
                                          ((quad ^ sws) * 8)];               \
        _Pragma("unroll")                                                    \
        for (int mi = 0; mi < 4; mi++)                                       \
            _Pragma("unroll")                                                \
            for (int ni = 0; ni < 4; ni++)                                   \
                acc[mi][ni] = __builtin_amdgcn_mfma_f32_16x16x32_f16(        \
                    af[mi], bf[ni], acc[mi][ni], 0, 0, 0);                   \
    } while (0)

    f16* pc = sm;            // compute buffer (t)
    f16* pn = sm + 8192;     // next (t+1)
    f16* pf = sm + 16384;    // staging target (t+2)
    STAGE(pc);
    STAGE(pn);
    for (int kt = 0; kt < 14; kt++) {
        asm volatile("s_waitcnt vmcnt(4)" ::: "memory");
        __builtin_amdgcn_s_barrier();
        __builtin_amdgcn_sched_barrier(0);
        STAGE(pf);
        COMPUTE(pc);
        f16* tmp = pc; pc = pn; pn = pf; pf = tmp;
    }
    asm volatile("s_waitcnt vmcnt(4)" ::: "memory");
    __builtin_amdgcn_s_barrier();
    __builtin_amdgcn_sched_barrier(0);
    COMPUTE(pc);
    { f16* tmp = pc; pc = pn; pn = pf; pf = tmp; }
    asm volatile("s_waitcnt vmcnt(0)" ::: "memory");
    __builtin_amdgcn_s_barrier();
    __builtin_amdgcn_sched_barrier(0);
    COMPUTE(pc);
#undef STAGE
#undef COMPUTE

    __syncthreads();   // all waves done reading LDS; reuse as per-wave bounce

    if constexpr (MODE == MODE_PROJ) {
        float* pwf = (float*)sm + w * 1088;
        const int rr4 = lane >> 4, c4c = (lane & 15) * 4;
        float4v bb = *(const float4v*)&bias[n0 + wn * 64 + c4c];
        #pragma unroll
        for (int mi = 0; mi < 4; mi++) {
            #pragma unroll
            for (int ni = 0; ni < 4; ni++)
                #pragma unroll
                for (int i = 0; i < 4; i++)
                    pwf[(quad * 4 + i) * 68 + ni * 16 + l15] = acc[mi][ni][i];
            #pragma unroll
            for (int s = 0; s < 4; s++) {
                int r = s * 4 + rr4;
                float4v v = *(const float4v*)&pwf[r * 68 + c4c];
                *(float4v*)&outf[(size_t)(m0 + wm * 64 + mi * 16 + r) * 512 +
                                 n0 + wn * 64 + c4c] = v + bb;
            }
        }
    } else {
        f16* pw = sm + w * 2304;
        const int rr8 = lane >> 3, c8 = (lane & 7) * 8;
        #pragma unroll
        for (int hf = 0; hf < 2; hf++) {
            #pragma unroll
            for (int mh = 0; mh < 2; mh++) {
                int mi = hf * 2 + mh;
                #pragma unroll
                for (int ni = 0; ni < 4; ni++)
                    #pragma unroll
                    for (int i = 0; i < 4; i++)
                        pw[(mh * 16 + quad * 4 + i) * 72 + ni * 16 + l15] =
                            (f16)acc[mi][ni][i];
            }
            #pragma unroll
            for (int s = 0; s < 4; s++) {
                int r = s * 8 + rr8;
                half8 v = *(const half8*)&pw[r * 72 + c8];
                int gr = m0 + wm * 64 + hf * 32 + r;
                int gc = n0 + wn * 64 + c8;
                if constexpr (MODE == MODE_QK) {
                    int b = gr >> 9, n = gr & 511;
                    if (gc < 512)
                        *(half8*)&outa[(((size_t)(b * 8 + (gc >> 6))) * 512 + n) * 64 + (gc & 63)] = v;
                    else {
                        int jj = gc - 512;
                        *(half8*)&outb[(((size_t)(b * 8 + (jj >> 6))) * 512 + n) * 64 + (jj & 63)] = v;
                    }
                } else { // MODE_V
                    int h = gr >> 6, dd = gr & 63;   // e' order: p*64+dd
                    *(half8*)&outa[(((size_t)(vb * 8 + h)) * 1024 + vp * 64 + dd) * 512 + gc] = v;
                }
            }
        }
    }
}

// Fused flash-style attention: S = qk^T * 0.125, row softmax, P kept in LDS,
// then out = P @ vT^T written straight to ypre. Eliminates the P global
// round-trip (67 MB HBM) + PV's A-staging + one kernel launch.
// grid 512 = 8 ntiles x 64 bh (T1-swizzled: a bh's 8 blocks share one XCD so
// the 1 MB vT panel and 64 KB k panel are L2-resident); block 256 = 4 waves.
// LDS: [0,32768) f16 = k panel [512][64] (phases A/B), REUSED as P [64][512]
// (phase D+, one barrier between); [32768,37376) = 4 per-wave bounce regions.
// P swizzle: slot' = slot ^ ((row^(row>>3))&7); for row = mi*16+l15 this is
// swA ^ (mi<<1) with swA = (l15 ^ (l15>>3))&7  [the missing mi<<1 was the
// round-5 correctness bug].
// PV: A-frags from LDS P (zero staging), B-frags (vT rows) direct from L2
// with 1-deep register prefetch; 4 E'-chunks of 4x4 fragments per wave.
__global__ __launch_bounds__(256) void attn_pv_kernel(
    const f16* __restrict__ q, const f16* __restrict__ k,
    const f16* __restrict__ vT, f16* __restrict__ ypre)
{
    __shared__ __align__(16) f16 sm[37376];   // 74752 B -> 2 blocks/CU
    const int t = threadIdx.x;
    const int lane = t & 63, w = t >> 6;
    const int quad = lane >> 4, l15 = lane & 15;
    const int L = ((int)blockIdx.x & 7) * 64 + ((int)blockIdx.x >> 3);
    const int bh = L >> 3;
    const int n0 = (L & 7) * 64;

    // ---- Phase A: stage k panel [512][64] swizzled; q frags overlap ----
    const f16* kbase = k + (size_t)bh * 512 * 64;
    #pragma unroll
    for (int i = 0; i < 16; i++) {
        int cid = i * 256 + t;
        int row = cid >> 3, off = cid & 7;
        gload16(kbase + row * 64 + ((off ^ (row & 7)) << 3),
                sm + i * 2048 + w * 512 + lane * 8);
    }
    const f16* qp = q + ((size_t)bh * 512 + n0 + w * 16 + l15) * 64 + quad * 8;
    half8 a0 = *(const half8*)qp;
    half8 a1 = *(const half8*)(qp + 32);

    asm volatile("s_waitcnt vmcnt(0)" ::: "memory");
    __builtin_amdgcn_s_barrier();
    __builtin_amdgcn_sched_barrier(0);

    // ---- Phase B: S = q k^T (wave w owns local rows w*16..w*16+16) ----
    float4v acc[32];
    #pragma unroll
    for (int f = 0; f < 32; f++) acc[f] = (float4v){0.f, 0.f, 0.f, 0.f};
    #pragma unroll
    for (int fl = 0; fl < 32; fl++) {
        int row16 = fl * 16 + l15;
        int sw = row16 & 7;
        half8 b0 = *(const half8*)&sm[row16 * 64 + ((quad ^ sw) << 3)];
        half8 b1 = *(const half8*)&sm[row16 * 64 + (((quad + 4) ^ sw) << 3)];
        acc[fl] = __builtin_amdgcn_mfma_f32_16x16x32_f16(a0, b0, acc[fl], 0, 0, 0);
        acc[fl] = __builtin_amdgcn_mfma_f32_16x16x32_f16(a1, b1, acc[fl], 0, 0, 0);
    }

    // ---- Phase C: softmax (reduce over l15 within quad + in-thread f) ----
    float mx0 = -3e38f, mx1 = -3e38f, mx2 = -3e38f, mx3 = -3e38f;
    #pragma unroll
    for (int f = 0; f < 32; f++) {
        mx0 = fmaxf(mx0, acc[f][0]); mx1 = fmaxf(mx1, acc[f][1]);
        mx2 = fmaxf(mx2, acc[f][2]); mx3 = fmaxf(mx3, acc[f][3]);
    }
    #pragma unroll
    for (int off = 1; off < 16; off <<= 1) {
        mx0 = fmaxf(mx0, __shfl_xor(mx0, off));
        mx1 = fmaxf(mx1, __shfl_xor(mx1, off));
        mx2 = fmaxf(mx2, __shfl_xor(mx2, off));
        mx3 = fmaxf(mx3, __shfl_xor(mx3, off));
    }
    float s0 = 0.f, s1 = 0.f, s2 = 0.f, s3 = 0.f;
    #pragma unroll
    for (int f = 0; f < 32; f++) {
        float e0 = __expf(0.125f * (acc[f][0] - mx0));
        float e1 = __expf(0.125f * (acc[f][1] - mx1));
        float e2 = __expf(0.125f * (acc[f][2] - mx2));
        float e3 = __expf(0.125f * (acc[f][3] - mx3));
        acc[f][0] = e0; acc[f][1] = e1; acc[f][2] = e2; acc[f][3] = e3;
        s0 += e0; s1 += e1; s2 += e2; s3 += e3;
    }
    #pragma unroll
    for (int off = 1; off < 16; off <<= 1) {
        s0 += __shfl_xor(s0, off);
        s1 += __shfl_xor(s1, off);
        s2 += __shfl_xor(s2, off);
        s3 += __shfl_xor(s3, off);
    }
    float rr[4];
    rr[0] = 1.f / s0; rr[1] = 1.f / s1; rr[2] = 1.f / s2; rr[3] = 1.f / s3;

    // ---- Phase D: P (f16, normalized) -> LDS [64][512] swizzled ----
    __syncthreads();               // all waves done reading the k panel
    {
        const int prow_b = w * 16 + quad * 4;
        #pragma unroll
        for (int f = 0; f < 32; f++) {
            #pragma unroll
            for (int i = 0; i < 4; i++) {
                int row = prow_b + i;
                int col = f * 16 + l15;
                int slot = (col >> 3) ^ ((row ^ (row >> 3)) & 7);
                sm[row * 512 + slot * 8 + (col & 7)] = (f16)(acc[f][i] * rr[i]);
            }
        }
    }
    __syncthreads();               // P visible to all waves

    // ---- Phase E: out = P @ vT^T, per wave one 64-wide E' stripe/chunk ----
    const int swA = (l15 ^ (l15 >> 3)) & 7;
    const f16* vbase = vT + (size_t)bh * 1024 * 512;
    const int b_ = bh >> 3, h_ = bh & 7;
    f16* pw = sm + 32768 + w * 1152;          // per-wave [16][72] bounce
    for (int ec = 0; ec < 4; ec++) {
        const f16* vb = vbase + (size_t)(ec * 256 + w * 64) * 512;
        float4v acc2[4][4];
        #pragma unroll
        for (int mi = 0; mi < 4; mi++)
            #pragma unroll
            for (int nf = 0; nf < 4; nf++)
                acc2[mi][nf] = (float4v){0.f, 0.f, 0.f, 0.f};
        half8 bc[4], bn_[4];
        #pragma unroll
        for (int nf = 0; nf < 4; nf++)
            bc[nf] = *(const half8*)&vb[(size_t)(nf * 16 + l15) * 512 + quad * 8];
        #pragma unroll
        for (int ks = 0; ks < 16; ks++) {
            if (ks < 15) {
                #pragma unroll
                for (int nf = 0; nf < 4; nf++)
                    bn_[nf] = *(const half8*)&vb[(size_t)(nf * 16 + l15) * 512 +
                                                 (ks + 1) * 32 + quad * 8];
            }
            half8 af[4];
            #pragma unroll
            for (int mi = 0; mi < 4; mi++)
                af[mi] = *(const half8*)&sm[(mi * 16 + l15) * 512 +
                                            (((ks * 4 + quad) ^ swA ^ (mi << 1)) << 3)];
            #pragma unroll
            for (int mi = 0; mi < 4; mi++)
                #pragma unroll
                for (int nf = 0; nf < 4; nf++)
                    acc2[mi][nf] = __builtin_amdgcn_mfma_f32_16x16x32_f16(
                        af[mi], bc[nf], acc2[mi][nf], 0, 0, 0);
            #pragma unroll
            for (int nf = 0; nf < 4; nf++) bc[nf] = bn_[nf];
        }
        // epilogue for this chunk: e' = ec*256 + w*64 + nf*16 + l15
        // -> single p = ec*4 + w, dd = nf*16 + l15
        const int p_of = ec * 4 + w;
        const int r = lane >> 2, c16 = (lane & 3) * 16;
        #pragma unroll
        for (int mi = 0; mi < 4; mi++) {
            #pragma unroll
            for (int nf = 0; nf < 4; nf++)
                #pragma unroll
                for (int i = 0; i < 4; i++)
                    pw[(quad * 4 + i) * 72 + nf * 16 + l15] = (f16)acc2[mi][nf][i];
            int n_ = n0 + mi * 16 + r;
            size_t gb = ((size_t)(b_ * 512 + n_) * 16 + p_of) * 512 + h_ * 64 + c16;
            half8 v0 = *(const half8*)&pw[r * 72 + c16];
            half8 v1 = *(const half8*)&pw[r * 72 + c16 + 8];
            *(half8*)&ypre[gb] = v0;
            *(half8*)&ypre[gb + 8] = v1;
        }
    }
}

extern "C" void kernel_launch(void* const* d_in, const int* in_sizes, int n_in,
                              void* d_out, int out_size, void* d_ws, size_t ws_size,
                              hipStream_t stream)
{
    (void)in_sizes; (void)n_in; (void)out_size; (void)ws_size;
    const float* x     = (const float*)d_in[0];
    const float* mask  = (const float*)d_in[1];
    // d_in[2] lens, d_in[3] lens_mask: unused by the reference forward
    const float* Wqkv  = (const float*)d_in[4];
    const float* Wproj = (const float*)d_in[5];
    const float* bproj = (const float*)d_in[6];
    float* out = (float*)d_out;
    char* ws = (char*)d_ws;

    f16* xf16  = (f16*)(ws + 0);
    f16* vT    = (f16*)(ws + 67108864);
    f16* xmean = (f16*)(ws + 134217728);
    f16* WT    = (f16*)(ws + 138412032);
    f16* WpT   = (f16*)(ws + 139984896);
    f16* qb    = (f16*)(ws + 140509184);
    f16* kb    = (f16*)(ws + 144703488);
    f16* ypre  = xf16;   // xf16 dead after V GEMM; fused attn writes here

    prep_kernel<<<dim3(8192), dim3(256), 0, stream>>>(
        x, mask, Wqkv, Wproj, xf16, xmean, WT, WpT);
    gemm128<MODE_QK, 3, 5><<<dim3(256), dim3(256), 0, stream>>>(
        xf16, xmean, WT, qb, kb, nullptr, nullptr);
    gemm128<MODE_V, 2, 2><<<dim3(2048), dim3(256), 0, stream>>>(
        WT + 1024 * 512, nullptr, xf16, vT, nullptr, nullptr, nullptr);
    attn_pv_kernel<<<dim3(512), dim3(256), 0, stream>>>(qb, kb, vT, ypre);
    gemm128<MODE_PROJ, 2, 9><<<dim3(2048), dim3(256), 0, stream>>>(
        ypre, nullptr, WpT, nullptr, nullptr, out, bproj);
}